// Round 1
// baseline (56.097 us; speedup 1.0000x reference)
//
#include <hip/hip_runtime.h>
#include <math.h>

// Problem constants (fixed by setup_inputs)
#define BB 16
#define JJ 18
#define DD 64
#define HH 64
#define WW 64
#define HM (DD * HH * WW)        // 262144 elements per heatmap
#define NHM (BB * JJ)            // 288 heatmaps
#define SLICES 8                 // blocks per heatmap
#define CHUNK (HM / SLICES)      // 32768 elements per block
#define T1 256                   // threads per block (4 waves)
#define ITERS (CHUNK / (T1 * 4)) // 32 float4 iterations per thread

// Combine two online-softmax partial states (deterministic).
__device__ __forceinline__ void combine(float& m, float& s, float& sx, float& sy, float& sz,
                                        float m2, float s2, float sx2, float sy2, float sz2) {
    float M = fmaxf(m, m2);
    float a = __expf(m - M);   // exp(-inf)=0 handles empty state
    float b = __expf(m2 - M);
    s  = s  * a + s2  * b;
    sx = sx * a + sx2 * b;
    sy = sy * a + sy2 * b;
    sz = sz * a + sz2 * b;
    m = M;
}

// Kernel 1: each block processes one contiguous 32768-element slice of one
// heatmap. Online softmax with coordinate-weighted sums. Writes 5-float
// partial (m, S, Sx, Sy, Sz) per block to ws.
__global__ __launch_bounds__(T1) void partial_kernel(const float* __restrict__ preds,
                                                     float* __restrict__ ws) {
    const int blk = blockIdx.x;           // 0 .. NHM*SLICES-1; heatmap = blk/SLICES
    const int t = threadIdx.x;
    const int slice = blk & (SLICES - 1);

    // Chunks are globally contiguous: float offset = blk * CHUNK (16B aligned).
    const float4* base = reinterpret_cast<const float4*>(preds) + (size_t)blk * (CHUNK / 4);

    float m = -INFINITY, s = 0.f, sx = 0.f, sy = 0.f, sz = 0.f;
    int eh = slice * CHUNK + t * 4;       // element index within the heatmap

#pragma unroll 4
    for (int i = 0; i < ITERS; ++i) {
        float4 v = base[i * T1 + t];
        // flat index e = d*4096 + h*64 + w  (row-major D,H,W)
        float zc = (float)(eh >> 12);
        float hc = (float)((eh >> 6) & 63);
        float wc = (float)(eh & 63);      // w of v.x; v.y/z/w are wc+1,+2,+3

        float mx = fmaxf(fmaxf(v.x, v.y), fmaxf(v.z, v.w));
        float nm = fmaxf(m, mx);
        float r = __expf(m - nm);         // ==1 almost always after warmup
        s *= r; sx *= r; sy *= r; sz *= r;
        m = nm;

        float e0 = __expf(v.x - m);
        float e1 = __expf(v.y - m);
        float e2 = __expf(v.z - m);
        float e3 = __expf(v.w - m);
        float sw = (e0 + e1) + (e2 + e3);
        s += sw;
        sx += fmaf(sw, wc, fmaf(2.f, e2, e1) + 3.f * e3);
        sy = fmaf(sw, hc, sy);
        sz = fmaf(sw, zc, sz);

        eh += T1 * 4;
    }

    // Wave (64-lane) butterfly reduction.
#pragma unroll
    for (int off = 32; off > 0; off >>= 1) {
        float m2  = __shfl_xor(m, off);
        float s2  = __shfl_xor(s, off);
        float sx2 = __shfl_xor(sx, off);
        float sy2 = __shfl_xor(sy, off);
        float sz2 = __shfl_xor(sz, off);
        combine(m, s, sx, sy, sz, m2, s2, sx2, sy2, sz2);
    }

    __shared__ float red[4][5];
    const int wave = t >> 6;
    const int lane = t & 63;
    if (lane == 0) {
        red[wave][0] = m; red[wave][1] = s; red[wave][2] = sx;
        red[wave][3] = sy; red[wave][4] = sz;
    }
    __syncthreads();
    if (t == 0) {
        for (int wv = 1; wv < 4; ++wv)
            combine(m, s, sx, sy, sz,
                    red[wv][0], red[wv][1], red[wv][2], red[wv][3], red[wv][4]);
        float* o = ws + (size_t)blk * 5;
        o[0] = m; o[1] = s; o[2] = sx; o[3] = sy; o[4] = sz;
    }
}

// Kernel 2: single block. Thread j (< 288) merges its heatmap's 8 partials,
// computes soft-argmax coords and the per-joint weighted MSE contribution;
// block-reduce and write out[0] = total / B.
__global__ __launch_bounds__(320) void finalize_kernel(const float* __restrict__ ws,
                                                       const float* __restrict__ gt,
                                                       const float* __restrict__ vis,
                                                       float* __restrict__ out) {
    const int t = threadIdx.x;
    float loss = 0.f;
    if (t < NHM) {
        float m = -INFINITY, s = 0.f, sx = 0.f, sy = 0.f, sz = 0.f;
        const float* p = ws + (size_t)t * SLICES * 5;
        for (int c = 0; c < SLICES; ++c)
            combine(m, s, sx, sy, sz,
                    p[c * 5 + 0], p[c * 5 + 1], p[c * 5 + 2], p[c * 5 + 3], p[c * 5 + 4]);
        float inv = 1.f / s;
        float ax = sx * inv * (1.f / (float)WW) - 0.5f;
        float ay = sy * inv * (1.f / (float)HH) - 0.5f;
        float az = sz * inv * (1.f / (float)DD) - 0.5f;
        const int b = t / JJ, j = t % JJ;
        // pred_jts row layout: [x_j, y_j, z_j] interleaved -> gt index b*3J + 3j + k
        const float* g  = gt  + b * (3 * JJ) + 3 * j;
        const float* vv = vis + b * (3 * JJ) + 3 * j;
        float dx = ax - g[0], dy = ay - g[1], dz = az - g[2];
        loss = dx * dx * vv[0] + dy * dy * vv[1] + dz * dz * vv[2];
    }

#pragma unroll
    for (int off = 32; off > 0; off >>= 1)
        loss += __shfl_xor(loss, off);

    __shared__ float part[5];
    const int wave = t >> 6;
    const int lane = t & 63;
    if (lane == 0) part[wave] = loss;
    __syncthreads();
    if (t == 0) {
        float tot = (part[0] + part[1]) + (part[2] + part[3]) + part[4];
        out[0] = tot * (1.f / (float)BB);
    }
}

extern "C" void kernel_launch(void* const* d_in, const int* in_sizes, int n_in,
                              void* d_out, int out_size, void* d_ws, size_t ws_size,
                              hipStream_t stream) {
    const float* preds = (const float*)d_in[0];
    const float* gt    = (const float*)d_in[1];
    const float* vis   = (const float*)d_in[2];
    float* out = (float*)d_out;
    float* ws  = (float*)d_ws;   // needs NHM*SLICES*5*4 = 46080 bytes

    partial_kernel<<<NHM * SLICES, T1, 0, stream>>>(preds, ws);
    finalize_kernel<<<1, 320, 0, stream>>>(ws, gt, vis, out);
}